// Round 1
// baseline (650.522 us; speedup 1.0000x reference)
//
#include <hip/hip_runtime.h>

#define DIMS 384
#define SLOPE 0.01f

typedef __attribute__((ext_vector_type(8))) short s16x8;
typedef __attribute__((ext_vector_type(8))) unsigned short u16x8;
typedef __attribute__((ext_vector_type(4))) float f32x4;

__device__ __forceinline__ unsigned short f2bf(float f) {
  unsigned u = __float_as_uint(f);
  unsigned r = (u + 0x7FFFu + ((u >> 16) & 1u)) >> 16;
  return (unsigned short)r;
}

__device__ __forceinline__ float leaky(float f) { return f >= 0.f ? f : SLOPE * f; }

// ---------------- graph preprocessing ----------------

__global__ void count_kernel(const int* __restrict__ dst, int* __restrict__ cnt, int E) {
  int e = blockIdx.x * blockDim.x + threadIdx.x;
  if (e < E) atomicAdd(&cnt[dst[e]], 1);
}

__global__ void dinv_kernel(const int* __restrict__ cnt, float* __restrict__ dinv, int n) {
  int i = blockIdx.x * blockDim.x + threadIdx.x;
  if (i < n) dinv[i] = 1.0f / sqrtf((float)(cnt[i] + 1));  // +1 self loop
}

__global__ void scan1_kernel(const int* __restrict__ cnt, int* __restrict__ off,
                             int* __restrict__ bsum, int n) {
  __shared__ int s[256];
  int tid = threadIdx.x, gid = blockIdx.x * 256 + tid;
  int v = gid < n ? cnt[gid] : 0;
  s[tid] = v;
  __syncthreads();
  for (int o = 1; o < 256; o <<= 1) {
    int t = tid >= o ? s[tid - o] : 0;
    __syncthreads();
    s[tid] += t;
    __syncthreads();
  }
  if (gid < n) off[gid] = s[tid] - v;  // exclusive within block
  if (tid == 255) bsum[blockIdx.x] = s[255];
}

__global__ void scan2_kernel(const int* __restrict__ bsum, int* __restrict__ boff, int nb) {
  __shared__ int s[512];
  int tid = threadIdx.x;
  int v = tid < nb ? bsum[tid] : 0;
  s[tid] = v;
  __syncthreads();
  for (int o = 1; o < 512; o <<= 1) {
    int t = tid >= o ? s[tid - o] : 0;
    __syncthreads();
    s[tid] += t;
    __syncthreads();
  }
  if (tid < nb) boff[tid] = s[tid] - v;
}

__global__ void scan3_kernel(int* __restrict__ off, const int* __restrict__ boff,
                             int* __restrict__ cursor, int n, int E) {
  int gid = blockIdx.x * 256 + threadIdx.x;
  if (gid < n) {
    int v = off[gid] + boff[gid >> 8];
    off[gid] = v;
    cursor[gid] = v;
  }
  if (gid == 0) off[n] = E;
}

__global__ void fill_kernel(const int* __restrict__ src, const int* __restrict__ dst,
                            const float* __restrict__ dinv, int* __restrict__ cursor,
                            int* __restrict__ csr_s, float* __restrict__ csr_w, int E) {
  int e = blockIdx.x * blockDim.x + threadIdx.x;
  if (e >= E) return;
  int d = dst[e], s = src[e];
  int p = atomicAdd(&cursor[d], 1);
  csr_s[p] = s;
  csr_w[p] = dinv[s] * dinv[d];
}

// W [K][384] row-major -> Wt [384][K] bf16
__global__ void wt_kernel(const float* __restrict__ W, unsigned short* __restrict__ Wt, int K) {
  int idx = blockIdx.x * blockDim.x + threadIdx.x;
  if (idx >= K * DIMS) return;
  int k = idx / DIMS, nn = idx - k * DIMS;
  Wt[nn * K + k] = f2bf(W[idx]);
}

// ---------------- GEMM: H[M][384] = A[M][K] @ W[K][384] via bf16 MFMA ----------------
// LAYER 1: A = x (f32). LAYER 2: A = leaky(concat(x, y)); k<384 from x (leaky on the
// fly), k>=384 from YBL (bf16, already leaky'd).

template <int LAYER>
__launch_bounds__(256, 2)
__global__ void gemm_kernel(const float* __restrict__ X, const unsigned short* __restrict__ YBL,
                            const unsigned short* __restrict__ Wt, float* __restrict__ H,
                            int M, int K) {
  __shared__ unsigned short As[128][32];  // [row][k] 64B rows
  __shared__ unsigned short Bs[128][32];  // [col][k]
  const int tid = threadIdx.x;
  const int lane = tid & 63;
  const int wave = tid >> 6;
  const int wr = (wave >> 1) * 64;
  const int wc = (wave & 1) * 64;
  const int row0 = blockIdx.x * 128;
  const int n0 = blockIdx.y * 128;
  const int sr = tid >> 1;
  const int sc = (tid & 1) * 16;
  const int fr = lane & 15;
  const int kq = (lane >> 4) * 8;
  f32x4 acc[4][4] = {};

  for (int k0 = 0; k0 < K; k0 += 32) {
    __syncthreads();
    // stage A (128 x 32)
    {
      const int grow = row0 + sr;
      if (LAYER == 2 && k0 >= DIMS) {
        u16x8 v0, v1;
        if (grow < M) {
          const u16x8* p = (const u16x8*)(YBL + (size_t)grow * DIMS + (k0 - DIMS) + sc);
          v0 = p[0];
          v1 = p[1];
        } else {
#pragma unroll
          for (int j = 0; j < 8; j++) { v0[j] = 0; v1[j] = 0; }
        }
        *(u16x8*)&As[sr][sc] = v0;
        *(u16x8*)&As[sr][sc + 8] = v1;
      } else {
        float fv[16];
        if (grow < M) {
          const float4* p = (const float4*)(X + (size_t)grow * DIMS + k0 + sc);
#pragma unroll
          for (int q = 0; q < 4; q++) {
            float4 f = p[q];
            fv[4 * q] = f.x; fv[4 * q + 1] = f.y; fv[4 * q + 2] = f.z; fv[4 * q + 3] = f.w;
          }
        } else {
#pragma unroll
          for (int j = 0; j < 16; j++) fv[j] = 0.f;
        }
        u16x8 o0, o1;
#pragma unroll
        for (int j = 0; j < 8; j++) {
          float f = fv[j], g = fv[8 + j];
          if (LAYER == 2) { f = leaky(f); g = leaky(g); }
          o0[j] = f2bf(f);
          o1[j] = f2bf(g);
        }
        *(u16x8*)&As[sr][sc] = o0;
        *(u16x8*)&As[sr][sc + 8] = o1;
      }
    }
    // stage B (128 cols x 32 k) from pre-transposed Wt[n][k]
    {
      const u16x8* p = (const u16x8*)(Wt + (size_t)(n0 + sr) * K + k0 + sc);
      *(u16x8*)&Bs[sr][sc] = p[0];
      *(u16x8*)&Bs[sr][sc + 8] = p[1];
    }
    __syncthreads();

    s16x8 av[4], bv[4];
#pragma unroll
    for (int m = 0; m < 4; m++) av[m] = *(const s16x8*)&As[wr + m * 16 + fr][kq];
#pragma unroll
    for (int nn = 0; nn < 4; nn++) bv[nn] = *(const s16x8*)&Bs[wc + nn * 16 + fr][kq];
#pragma unroll
    for (int m = 0; m < 4; m++)
#pragma unroll
      for (int nn = 0; nn < 4; nn++)
        acc[m][nn] = __builtin_amdgcn_mfma_f32_16x16x32_bf16(av[m], bv[nn], acc[m][nn], 0, 0, 0);
  }

  // epilogue: D mapping col=lane&15, row=(lane>>4)*4+j  [guide m89/m91]
  const int rq = (lane >> 4) * 4;
#pragma unroll
  for (int m = 0; m < 4; m++) {
#pragma unroll
    for (int nn = 0; nn < 4; nn++) {
      const int col = n0 + wc + nn * 16 + fr;
#pragma unroll
      for (int j = 0; j < 4; j++) {
        const int row = row0 + wr + m * 16 + rq + j;
        if (row < M) H[(size_t)row * DIMS + col] = acc[m][nn][j];
      }
    }
  }
}

// ---------------- aggregation: out[i] = bias + dinv[i]^2*H[i] + sum_in w*H[src] --------
// MODE 1: write bf16 with leaky (layer-1 y buffer). MODE 2: write f32 raw (z_pre).

template <int MODE>
__global__ void agg_kernel(const float* __restrict__ H, const float* __restrict__ bias,
                           const float* __restrict__ dinv, const int* __restrict__ off,
                           const int* __restrict__ csr_s, const float* __restrict__ csr_w,
                           void* __restrict__ outp, int n) {
  const int wid = (blockIdx.x * blockDim.x + threadIdx.x) >> 6;
  const int lane = threadIdx.x & 63;
  if (wid >= n) return;
  const float ds = dinv[wid];
  const float ws = ds * ds;
  const float* hr = H + (size_t)wid * DIMS;
  float acc[6];
#pragma unroll
  for (int j = 0; j < 6; j++) acc[j] = bias[lane + 64 * j] + ws * hr[lane + 64 * j];
  const int e1 = off[wid + 1];
  for (int e = off[wid]; e < e1; e++) {
    const int s = csr_s[e];
    const float w = csr_w[e];
    const float* hs = H + (size_t)s * DIMS;
#pragma unroll
    for (int j = 0; j < 6; j++) acc[j] += w * hs[lane + 64 * j];
  }
  if (MODE == 1) {
    unsigned short* o = (unsigned short*)outp + (size_t)wid * DIMS;
#pragma unroll
    for (int j = 0; j < 6; j++) o[lane + 64 * j] = f2bf(leaky(acc[j]));
  } else {
    float* o = (float*)outp + (size_t)wid * DIMS;
#pragma unroll
    for (int j = 0; j < 6; j++) o[lane + 64 * j] = acc[j];
  }
}

// ---------------- finalize: z = leaky(z_pre) in place; a = z @ Wp + bp ----------------

__global__ void final_kernel(float* __restrict__ Z, const float* __restrict__ Wp,
                             const float* __restrict__ bp, float* __restrict__ A, int n) {
  const int wid = (blockIdx.x * blockDim.x + threadIdx.x) >> 6;
  const int lane = threadIdx.x & 63;
  if (wid >= n) return;
  float* zr = Z + (size_t)wid * DIMS;
  float dot = 0.f;
#pragma unroll
  for (int j = 0; j < 6; j++) {
    float f = leaky(zr[lane + 64 * j]);
    zr[lane + 64 * j] = f;
    dot += f * Wp[lane + 64 * j];
  }
#pragma unroll
  for (int o = 32; o > 0; o >>= 1) dot += __shfl_xor(dot, o);
  if (lane == 0) A[wid] = dot + bp[0];
}

// ---------------- launch ----------------

extern "C" void kernel_launch(void* const* d_in, const int* in_sizes, int n_in,
                              void* d_out, int out_size, void* d_ws, size_t ws_size,
                              hipStream_t stream) {
  const float* x = (const float*)d_in[0];
  const int* ei = (const int*)d_in[1];
  const float* W1 = (const float*)d_in[2];
  const float* b1 = (const float*)d_in[3];
  const float* W2 = (const float*)d_in[4];
  const float* b2 = (const float*)d_in[5];
  const float* Wp = (const float*)d_in[6];
  const float* bp = (const float*)d_in[7];
  const int N = in_sizes[0] / DIMS;  // 100000
  const int E = in_sizes[1] / 2;     // 400000
  const int* src = ei;
  const int* dst = ei + E;

  char* p = (char*)d_ws;
  auto alloc = [&](size_t bytes) {
    char* r = p;
    p += (bytes + 255) & ~(size_t)255;
    return r;
  };
  float* h = (float*)alloc((size_t)N * DIMS * 4);            // h1, reused as h2
  unsigned short* ybl = (unsigned short*)alloc((size_t)N * DIMS * 2);  // leaky(y) bf16
  float* dinv = (float*)alloc((size_t)N * 4);
  int* cnt = (int*)alloc((size_t)N * 4);
  int* off = (int*)alloc((size_t)(N + 1) * 4);
  int* cursor = (int*)alloc((size_t)N * 4);
  int* bsum = (int*)alloc(4096);
  int* boff = (int*)alloc(4096);
  int* csr_s = (int*)alloc((size_t)E * 4);
  float* csr_w = (float*)alloc((size_t)E * 4);
  unsigned short* Wt1 = (unsigned short*)alloc((size_t)DIMS * DIMS * 2);
  unsigned short* Wt2 = (unsigned short*)alloc((size_t)DIMS * 2 * DIMS * 2);

  float* z = (float*)d_out;
  float* a = z + (size_t)N * DIMS;

  const int nbN = (N + 255) / 256;
  const int nbE = (E + 255) / 256;

  hipMemsetAsync(cnt, 0, (size_t)N * 4, stream);
  count_kernel<<<nbE, 256, 0, stream>>>(dst, cnt, E);
  dinv_kernel<<<nbN, 256, 0, stream>>>(cnt, dinv, N);
  scan1_kernel<<<nbN, 256, 0, stream>>>(cnt, off, bsum, N);
  scan2_kernel<<<1, 512, 0, stream>>>(bsum, boff, nbN);
  scan3_kernel<<<nbN, 256, 0, stream>>>(off, boff, cursor, N, E);
  fill_kernel<<<nbE, 256, 0, stream>>>(src, dst, dinv, cursor, csr_s, csr_w, E);
  wt_kernel<<<(DIMS * DIMS + 255) / 256, 256, 0, stream>>>(W1, Wt1, DIMS);
  wt_kernel<<<(2 * DIMS * DIMS + 255) / 256, 256, 0, stream>>>(W2, Wt2, 2 * DIMS);

  dim3 gg((N + 127) / 128, DIMS / 128);
  gemm_kernel<1><<<gg, 256, 0, stream>>>(x, nullptr, Wt1, h, N, DIMS);
  agg_kernel<1><<<(N + 3) / 4, 256, 0, stream>>>(h, b1, dinv, off, csr_s, csr_w, ybl, N);
  gemm_kernel<2><<<gg, 256, 0, stream>>>(x, ybl, Wt2, h, N, 2 * DIMS);
  agg_kernel<2><<<(N + 3) / 4, 256, 0, stream>>>(h, b2, dinv, off, csr_s, csr_w, z, N);
  final_kernel<<<(N + 3) / 4, 256, 0, stream>>>(z, Wp, bp, a, N);
}